// Round 5
// baseline (51.042 us; speedup 1.0000x reference)
//
#include <hip/hip_runtime.h>
#include <stdint.h>

// Problem constants
static constexpr int NB = 16;     // batch
static constexpr int CI = 32;     // in channels
static constexpr int CO = 64;     // out channels
static constexpr int HI = 224, WI = 224;
static constexpr int HO = 112, WO = 112;
static constexpr int HW = HI * WI;
static constexpr float EPS = 1e-5f;

typedef _Float16 h2 __attribute__((ext_vector_type(2)));

__device__ __forceinline__ h2 as_h2(uint32_t u) {
    union { uint32_t u; h2 h; } c; c.u = u; return c.h;
}
__device__ __forceinline__ uint32_t pack_h2(float a, float b) {
    union { uint32_t u; h2 h; } c;
    c.h = (h2){(_Float16)a, (_Float16)b};
    return c.u;
}

// Workspace layout (bytes): packed weights only.
static constexpr size_t OFF_WT2 = 3072;   // wbits: CO*12 u32 = 3072
static constexpr size_t OFF_A1  = 7168;   // wt2:   16*CO u32 = 4096
static constexpr size_t OFF_CC  = 7424;   // A1/Cc: CO f32 each
static constexpr size_t WS_NEED = 7680;

// Padded s_xb column index: breaks pg-stride-32B 4-way bank conflict, keeps
// every phase-2 uint4 read 16B-aligned (col 8*pg -> idx 12*pg).
__device__ __forceinline__ int XB(int c) { return c + ((c >> 3) << 2); }
static constexpr int XBW = 132 + ((132 / 8) << 2) + 4;   // 200 u32 per row

__global__ __launch_bounds__(256) void prep_kernel(
    const float* __restrict__ wbody,
    const float* __restrict__ g1, const float* __restrict__ b1,
    const float* __restrict__ m1, const float* __restrict__ v1,
    const float* __restrict__ wds,
    const float* __restrict__ g2, const float* __restrict__ b2,
    const float* __restrict__ m2, const float* __restrict__ v2,
    uint32_t* __restrict__ wbits, uint32_t* __restrict__ wt2,
    float* __restrict__ A1, float* __restrict__ Cc)
{
    int i = blockIdx.x * 256 + threadIdx.x;
    if (i < 16 * CO) {
        int ci2 = i >> 6, co = i & 63;
        float inv2 = g2[co] * rsqrtf(v2[co] + EPS);
        float w0 = wds[co * CI + 2 * ci2]     * inv2;
        float w1 = wds[co * CI + 2 * ci2 + 1] * inv2;
        wt2[i] = pack_h2(w0, w1);
    } else if (i < 16 * CO + CO * 9) {
        int j = i - 16 * CO;
        int co = j / 9, k = j % 9;
        uint32_t bits = 0u;
#pragma unroll
        for (int ci = 0; ci < CI; ++ci) {
            float wv = wbody[(co * CI + ci) * 9 + k];
            bits |= (uint32_t)(wv >= 0.0f) << ci;
        }
        wbits[co * 12 + k] = bits;
    } else if (i < 16 * CO + CO * 9 + CO) {
        int co = i - 16 * CO - CO * 9;
        float inv1 = g1[co] * rsqrtf(v1[co] + EPS);
        float inv2 = g2[co] * rsqrtf(v2[co] + EPS);
        A1[co] = -2.0f * inv1;
        Cc[co] = b1[co] - m1[co] * inv1 + b2[co] - m2[co] * inv2 + 288.0f * inv1;
    }
}

// Rolling-window pipelined kernel. Block = (b, 7-output-row group gg, 64-wide
// ow tile); grid = 16*16*2 = 512 = exactly 2 blocks/CU.
// s_xb = 5-slot circular buffer of input-row bit-masks; s_avg double-buffered.
// Per iteration i (output row oh0+i):
//   issue loads for output row i+1's two input rows (+halo col)   [fly under compute]
//   compute output row i (reads slots of rel rows 2i..2i+2, avg buf i&1)
//   process+store loaded rows into slots (2i+3)%5,(2i+4)%5  [disjoint from all
//     concurrently-readable slots -> race-free without a pre-store barrier]
//   one __syncthreads
__global__ __launch_bounds__(256) void fused_kernel(
    const float* __restrict__ x,
    const uint32_t* __restrict__ wbits, const uint32_t* __restrict__ wt2,
    const float* __restrict__ A1p, const float* __restrict__ Ccp,
    float* __restrict__ out)
{
    // XCD-chunked bijective swizzle: 512 = 8 * 64 -> each XCD owns 2 whole images.
    const int bid  = (blockIdx.x & 7) * 64 + (blockIdx.x >> 3);
    const int tile = bid & 1;
    const int gb   = bid >> 1;         // 0..255
    const int gg   = gb & 15;          // row group: output rows 7gg..7gg+6
    const int b    = gb >> 4;
    const int oh0  = 7 * gg;
    const int ow0  = tile * 64;
    const int t    = threadIdx.x;

    // LDS: 4000 + 8704 + 4096 + 3072 + 512 = 20,384 B
    __shared__ __align__(16) uint32_t s_xb[5][XBW];     // circular input-row masks
    __shared__ __align__(16) uint32_t s_avg[2][16][68]; // double-buffered avgpool
    __shared__ __align__(16) uint32_t s_wt2[16][64];
    __shared__ __align__(16) uint32_t s_wb[CO * 12];
    __shared__ float s_A1[CO], s_C[CO];

    // ---- Burst 0: weight loads ----
    uint32_t wtv[4], wbv[3];
    float a1v = 0.f, ccv = 0.f;
#pragma unroll
    for (int i = 0; i < 4; ++i) wtv[i] = wt2[t + 256 * i];
#pragma unroll
    for (int i = 0; i < 3; ++i) wbv[i] = wbits[t + 256 * i];
    if (t < CO) { a1v = A1p[t]; ccv = Ccp[t]; }

    // derive mapping: thread (q = ch-group of 4, f = col-group of 4)
    const int q    = t & 7;            // channels 4q..4q+3
    const int f    = t >> 3;           // input cols 4f..4f+3 (rel to 2*ow0)
    const int jcol = 2 * ow0 + 4 * f;
    const bool colok = (jcol + 3 < WI);
    const int wc   = 2 * ow0 - 1;      // halo column (may be -1)

    // ---- Prologue loads: main rows 2oh0, 2oh0+1; halo row 2oh0-1; halo col ----
    float4 T[4], U[4], Hh[4];
#pragma unroll
    for (int j = 0; j < 4; ++j) {
        T[j] = make_float4(0.f, 0.f, 0.f, 0.f);
        U[j] = T[j]; Hh[j] = T[j];
    }
    {
        const float* base = x + ((size_t)(b * CI + 4 * q) * HI + 2 * oh0) * WI + jcol;
        if (colok) {
#pragma unroll
            for (int j = 0; j < 4; ++j) {
                T[j] = *(const float4*)(base + (size_t)j * HW);
                U[j] = *(const float4*)(base + (size_t)j * HW + WI);
            }
            if (gg > 0) {
#pragma unroll
                for (int j = 0; j < 4; ++j)
                    Hh[j] = *(const float4*)(base + (size_t)j * HW - WI);
            }
        }
    }
    float hcv[4] = {-1.f, -1.f, -1.f, -1.f};
    if (t < 24) {
        const int hr = 2 * oh0 - 1 + (t >> 3);
        if (hr >= 0 && wc >= 0) {
            const float* xc = x + ((size_t)(b * CI + 4 * q) * HI + hr) * WI + wc;
#pragma unroll
            for (int ci = 0; ci < 4; ++ci) hcv[ci] = xc[(size_t)ci * HW];
        }
    }

    // ---- Store weights to LDS (waits only burst-0 FIFO entries) ----
    {
        uint32_t* wt2s = (uint32_t*)s_wt2;
#pragma unroll
        for (int i = 0; i < 4; ++i) wt2s[t + 256 * i] = wtv[i];
#pragma unroll
        for (int i = 0; i < 3; ++i) s_wb[t + 256 * i] = wbv[i];
        if (t < CO) { s_A1[t] = a1v; s_C[t] = ccv; }
    }

    // process a loaded row-pair: bits into s_xb slots + avgpool into s_avg buf
    auto proc_pair = [&](const float4* Tv, const float4* Uv,
                         int slotT, int slotU, int av) {
        uint32_t mT[4] = {0, 0, 0, 0}, mU[4] = {0, 0, 0, 0};
#pragma unroll
        for (int j = 0; j < 4; ++j) {
            const int s = 4 * q + j;
            mT[0] |= (uint32_t)(Tv[j].x >= 0.f) << s;
            mT[1] |= (uint32_t)(Tv[j].y >= 0.f) << s;
            mT[2] |= (uint32_t)(Tv[j].z >= 0.f) << s;
            mT[3] |= (uint32_t)(Tv[j].w >= 0.f) << s;
            mU[0] |= (uint32_t)(Uv[j].x >= 0.f) << s;
            mU[1] |= (uint32_t)(Uv[j].y >= 0.f) << s;
            mU[2] |= (uint32_t)(Uv[j].z >= 0.f) << s;
            mU[3] |= (uint32_t)(Uv[j].w >= 0.f) << s;
        }
        // avgpool: ch pair (4q,4q+1) -> ci2=2q ; (4q+2,4q+3) -> ci2=2q+1
        float p00 = 0.25f * ((Tv[0].x + Tv[0].y) + (Uv[0].x + Uv[0].y));
        float p01 = 0.25f * ((Tv[0].z + Tv[0].w) + (Uv[0].z + Uv[0].w));
        float p10 = 0.25f * ((Tv[1].x + Tv[1].y) + (Uv[1].x + Uv[1].y));
        float p11 = 0.25f * ((Tv[1].z + Tv[1].w) + (Uv[1].z + Uv[1].w));
        float p20 = 0.25f * ((Tv[2].x + Tv[2].y) + (Uv[2].x + Uv[2].y));
        float p21 = 0.25f * ((Tv[2].z + Tv[2].w) + (Uv[2].z + Uv[2].w));
        float p30 = 0.25f * ((Tv[3].x + Tv[3].y) + (Uv[3].x + Uv[3].y));
        float p31 = 0.25f * ((Tv[3].z + Tv[3].w) + (Uv[3].z + Uv[3].w));
        *(uint2*)&s_avg[av][2 * q][2 * f] =
            make_uint2(pack_h2(p00, p10), pack_h2(p01, p11));
        *(uint2*)&s_avg[av][2 * q + 1][2 * f] =
            make_uint2(pack_h2(p20, p30), pack_h2(p21, p31));
        // OR-butterfly over the 8-lane (q) group -> full 32-bit masks
#pragma unroll
        for (int e = 0; e < 4; ++e) {
            mT[e] |= __shfl_xor(mT[e], 1); mT[e] |= __shfl_xor(mT[e], 2); mT[e] |= __shfl_xor(mT[e], 4);
            mU[e] |= __shfl_xor(mU[e], 1); mU[e] |= __shfl_xor(mU[e], 2); mU[e] |= __shfl_xor(mU[e], 4);
        }
        const int e = q & 3;
        uint32_t vT = (e == 0) ? mT[0] : (e == 1) ? mT[1] : (e == 2) ? mT[2] : mT[3];
        uint32_t vU = (e == 0) ? mU[0] : (e == 1) ? mU[1] : (e == 2) ? mU[2] : mU[3];
        if (q < 4) s_xb[slotT][XB(1 + 4 * f + e)] = vT;
        else       s_xb[slotU][XB(1 + 4 * f + e)] = vU;
    };

    // ---- Prologue processing: main pair -> slots 1,2 + avg buf 0; halo -> slot 0
    proc_pair(T, U, 1, 2, 0);
    {
        uint32_t mH[4] = {0, 0, 0, 0};
#pragma unroll
        for (int j = 0; j < 4; ++j) {
            const int s = 4 * q + j;
            mH[0] |= (uint32_t)(Hh[j].x >= 0.f) << s;
            mH[1] |= (uint32_t)(Hh[j].y >= 0.f) << s;
            mH[2] |= (uint32_t)(Hh[j].z >= 0.f) << s;
            mH[3] |= (uint32_t)(Hh[j].w >= 0.f) << s;
        }
        if (!(gg > 0 && colok)) { mH[0] = mH[1] = mH[2] = mH[3] = 0u; }
#pragma unroll
        for (int e = 0; e < 4; ++e) {
            mH[e] |= __shfl_xor(mH[e], 1); mH[e] |= __shfl_xor(mH[e], 2); mH[e] |= __shfl_xor(mH[e], 4);
        }
        if (q < 4) {
            uint32_t v = (q == 0) ? mH[0] : (q == 1) ? mH[1] : (q == 2) ? mH[2] : mH[3];
            s_xb[0][XB(1 + 4 * f + q)] = v;
        }
    }
    if (t < 24) {   // halo col rows rel 0..2 -> slots 0..2
        uint32_t bits = 0u;
#pragma unroll
        for (int ci = 0; ci < 4; ++ci)
            bits |= (uint32_t)(hcv[ci] >= 0.0f) << (4 * q + ci);
        bits |= __shfl_xor(bits, 1);
        bits |= __shfl_xor(bits, 2);
        bits |= __shfl_xor(bits, 4);
        if (q == 0) s_xb[t >> 3][XB(0)] = bits;
    }
    __syncthreads();

    // ---- compute machinery (proven body) ----
    const int cg  = t >> 4;
    const int pg  = t & 15;
    const int co0 = cg * 4;
    const int p0  = pg * 4;
    const bool pxvalid = (ow0 + p0 < WO);
    const bool px0 = (ow0 + p0 == 0);
    const int cb = 12 * pg;     // XB(8*pg)

    auto compute_row = [&](int i, int sA, int sB, int sC, int av) {
        float fa[4][4] = {{0.f,0.f,0.f,0.f},{0.f,0.f,0.f,0.f},{0.f,0.f,0.f,0.f},{0.f,0.f,0.f,0.f}};
#pragma unroll 4
        for (int ci2 = 0; ci2 < 16; ++ci2) {
            uint4 avv = *(const uint4*)&s_avg[av][ci2][p0];
            uint4 wvv = *(const uint4*)&s_wt2[ci2][co0];
            h2 a[4] = {as_h2(avv.x), as_h2(avv.y), as_h2(avv.z), as_h2(avv.w)};
            h2 w[4] = {as_h2(wvv.x), as_h2(wvv.y), as_h2(wvv.z), as_h2(wvv.w)};
#pragma unroll
            for (int jc = 0; jc < 4; ++jc)
#pragma unroll
                for (int jp = 0; jp < 4; ++jp)
                    fa[jc][jp] = __builtin_amdgcn_fdot2(w[jc], a[jp], fa[jc][jp], false);
        }
        uint32_t xr[3][9];
        const uint32_t* rows[3] = {s_xb[sA], s_xb[sB], s_xb[sC]};
#pragma unroll
        for (int rI = 0; rI < 3; ++rI) {
            uint4 a  = *(const uint4*)&rows[rI][cb];
            uint4 bq = *(const uint4*)&rows[rI][cb + 4];
            xr[rI][0] = a.x;  xr[rI][1] = a.y;  xr[rI][2] = a.z;  xr[rI][3] = a.w;
            xr[rI][4] = bq.x; xr[rI][5] = bq.y; xr[rI][6] = bq.z; xr[rI][7] = bq.w;
            xr[rI][8] = rows[rI][cb + 12];   // XB(8*pg + 8)
        }
        const bool ohf = (gg == 0 && i == 0);
        int sfin[4][4];
#pragma unroll
        for (int jc = 0; jc < 4; ++jc) {
            const int co = co0 + jc;
            uint4 wa  = *(const uint4*)&s_wb[co * 12];
            uint4 wb4 = *(const uint4*)&s_wb[co * 12 + 4];
            uint32_t wv[9] = {wa.x, wa.y, wa.z, wa.w, wb4.x, wb4.y, wb4.z, wb4.w,
                              s_wb[co * 12 + 8]};
#pragma unroll
            for (int jp = 0; jp < 4; ++jp) {
                int c00 = __popc(xr[0][2 * jp + 0] ^ wv[0]);
                int c01 = __popc(xr[0][2 * jp + 1] ^ wv[1]);
                int c02 = __popc(xr[0][2 * jp + 2] ^ wv[2]);
                int c10 = __popc(xr[1][2 * jp + 0] ^ wv[3]);
                int c11 = __popc(xr[1][2 * jp + 1] ^ wv[4]);
                int c12 = __popc(xr[1][2 * jp + 2] ^ wv[5]);
                int c20 = __popc(xr[2][2 * jp + 0] ^ wv[6]);
                int c21 = __popc(xr[2][2 * jp + 1] ^ wv[7]);
                int c22 = __popc(xr[2][2 * jp + 2] ^ wv[8]);
                int r0v  = c00 + c01 + c02;
                int ssum = r0v + c10 + c11 + c12 + c20 + c21 + c22;
                if (ohf) ssum += 48 - r0v;               // top image row
                if (px0 && jp == 0) {                    // left image column
                    ssum += 48 - (c00 + c10 + c20);
                    if (ohf) ssum += c00 - 16;           // corner double-fix
                }
                sfin[jc][jp] = ssum;
            }
        }
        if (pxvalid) {
#pragma unroll
            for (int jc = 0; jc < 4; ++jc) {
                const int co = co0 + jc;
                const float n2a = s_A1[co], cc = s_C[co];
                float4 o;
                o.x = fmaf(n2a, (float)sfin[jc][0], fa[jc][0] + cc);
                o.y = fmaf(n2a, (float)sfin[jc][1], fa[jc][1] + cc);
                o.z = fmaf(n2a, (float)sfin[jc][2], fa[jc][2] + cc);
                o.w = fmaf(n2a, (float)sfin[jc][3], fa[jc][3] + cc);
                *(float4*)&out[((size_t)(b * CO + co) * HO + (oh0 + i)) * WO + ow0 + p0] = o;
            }
        }
    };

    // ---- Main rolling loop over 7 output rows ----
    int sl0 = 0, sl1 = 1, sl2 = 2, sl3 = 3, sl4 = 4; // slots of rel rows 2i..2i+4
#pragma unroll 1
    for (int i = 0; i < 7; ++i) {
        const bool last = (i == 6);
        // issue next row-pair loads (fly under compute_row)
        float4 nT[4], nU[4];
#pragma unroll
        for (int j = 0; j < 4; ++j) {
            nT[j] = make_float4(0.f, 0.f, 0.f, 0.f);
            nU[j] = nT[j];
        }
        float nhc[4] = {-1.f, -1.f, -1.f, -1.f};
        if (!last) {
            const int r0 = 2 * oh0 + 2 * i + 2;
            if (colok) {
                const float* base = x + ((size_t)(b * CI + 4 * q) * HI + r0) * WI + jcol;
#pragma unroll
                for (int j = 0; j < 4; ++j) {
                    nT[j] = *(const float4*)(base + (size_t)j * HW);
                    nU[j] = *(const float4*)(base + (size_t)j * HW + WI);
                }
            }
            if (t < 16 && wc >= 0) {
                const float* xc = x + ((size_t)(b * CI + 4 * q) * HI + (r0 + (t >> 3))) * WI + wc;
#pragma unroll
                for (int ci = 0; ci < 4; ++ci) nhc[ci] = xc[(size_t)ci * HW];
            }
        }

        compute_row(i, sl0, sl1, sl2, i & 1);

        if (!last) {
            proc_pair(nT, nU, sl3, sl4, (i + 1) & 1);
            if (t < 16) {   // halo col for the two new rows -> slots sl3, sl4
                uint32_t bits = 0u;
#pragma unroll
                for (int ci = 0; ci < 4; ++ci)
                    bits |= (uint32_t)(nhc[ci] >= 0.0f) << (4 * q + ci);
                bits |= __shfl_xor(bits, 1);
                bits |= __shfl_xor(bits, 2);
                bits |= __shfl_xor(bits, 4);
                if (q == 0) s_xb[(t >> 3) == 0 ? sl3 : sl4][XB(0)] = bits;
            }
            __syncthreads();
        }
        // rotate slots: window advances by 2 rows
        int o0 = sl0, o1 = sl1;
        sl0 = sl2; sl1 = sl3; sl2 = sl4; sl3 = o0; sl4 = o1;
    }
}

// Fallback if workspace is too small: direct per-output computation (slow, correct).
__global__ __launch_bounds__(256) void naive_kernel(
    const float* __restrict__ x, const float* __restrict__ wbody,
    const float* __restrict__ g1, const float* __restrict__ b1,
    const float* __restrict__ m1, const float* __restrict__ v1,
    const float* __restrict__ wds,
    const float* __restrict__ g2, const float* __restrict__ b2,
    const float* __restrict__ m2, const float* __restrict__ v2,
    float* __restrict__ out)
{
    int i = blockIdx.x * 256 + threadIdx.x;
    if (i >= NB * CO * HO * WO) return;
    int ow = i % WO;
    int oh = (i / WO) % HO;
    int co = (i / (WO * HO)) % CO;
    int b  = i / (WO * HO * CO);
    float inv1 = g1[co] * rsqrtf(v1[co] + EPS);
    float inv2 = g2[co] * rsqrtf(v2[co] + EPS);
    int body = 0;
    float ds = 0.f;
    for (int ci = 0; ci < CI; ++ci) {
        const float* xp = x + (size_t)(b * CI + ci) * HW;
        for (int kh = 0; kh < 3; ++kh) {
            int hh = 2 * oh - 1 + kh;
            if (hh < 0 || hh >= HI) continue;
            for (int kw = 0; kw < 3; ++kw) {
                int ww = 2 * ow - 1 + kw;
                if (ww < 0 || ww >= WI) continue;
                float xv = xp[(size_t)hh * WI + ww];
                float wv = wbody[((co * CI + ci) * 3 + kh) * 3 + kw];
                int sx = (xv >= 0.f) ? 1 : -1;
                int sw = (wv >= 0.f) ? 1 : -1;
                body += sx * sw;
            }
        }
        float a = 0.25f * (xp[(size_t)(2 * oh) * WI + 2 * ow]
                         + xp[(size_t)(2 * oh) * WI + 2 * ow + 1]
                         + xp[(size_t)(2 * oh + 1) * WI + 2 * ow]
                         + xp[(size_t)(2 * oh + 1) * WI + 2 * ow + 1]);
        ds += a * wds[co * CI + ci];
    }
    out[i] = inv1 * (float)body + (b1[co] - m1[co] * inv1)
           + inv2 * ds + (b2[co] - m2[co] * inv2);
}

extern "C" void kernel_launch(void* const* d_in, const int* in_sizes, int n_in,
                              void* d_out, int out_size, void* d_ws, size_t ws_size,
                              hipStream_t stream)
{
    (void)in_sizes; (void)n_in; (void)out_size;
    const float* x   = (const float*)d_in[0];
    const float* wbd = (const float*)d_in[1];
    const float* g1  = (const float*)d_in[2];
    const float* b1  = (const float*)d_in[3];
    const float* m1  = (const float*)d_in[4];
    const float* v1  = (const float*)d_in[5];
    const float* wds = (const float*)d_in[6];
    const float* g2  = (const float*)d_in[7];
    const float* b2  = (const float*)d_in[8];
    const float* m2  = (const float*)d_in[9];
    const float* v2  = (const float*)d_in[10];
    float* out = (float*)d_out;

    if (ws_size < WS_NEED) {
        int total = NB * CO * HO * WO;
        naive_kernel<<<(total + 255) / 256, 256, 0, stream>>>(
            x, wbd, g1, b1, m1, v1, wds, g2, b2, m2, v2, out);
        return;
    }

    char* wsb = (char*)d_ws;
    uint32_t* wbits = (uint32_t*)wsb;
    uint32_t* wt2   = (uint32_t*)(wsb + OFF_WT2);
    float*    A1    = (float*)(wsb + OFF_A1);
    float*    Cc    = (float*)(wsb + OFF_CC);

    prep_kernel<<<7, 256, 0, stream>>>(wbd, g1, b1, m1, v1, wds, g2, b2, m2, v2,
                                       wbits, wt2, A1, Cc);
    // grid = 16 images * 16 row-groups * 2 ow tiles = 512 blocks (= 8 * 64)
    fused_kernel<<<dim3(512), 256, 0, stream>>>(
        x, wbits, wt2, A1, Cc, out);
}

// Round 6
// 44.925 us; speedup vs baseline: 1.1362x; 1.1362x over previous
//
#include <hip/hip_runtime.h>
#include <stdint.h>

// Problem constants
static constexpr int NB = 16;     // batch
static constexpr int CI = 32;     // in channels
static constexpr int CO = 64;     // out channels
static constexpr int HI = 224, WI = 224;
static constexpr int HO = 112, WO = 112;
static constexpr int HW = HI * WI;
static constexpr float EPS = 1e-5f;

typedef _Float16 h2 __attribute__((ext_vector_type(2)));
typedef _Float16 h8 __attribute__((ext_vector_type(8)));
typedef float f32x4 __attribute__((ext_vector_type(4)));

__device__ __forceinline__ h2 as_h2(uint32_t u) {
    union { uint32_t u; h2 h; } c; c.u = u; return c.h;
}
__device__ __forceinline__ uint32_t pack_h2(float a, float b) {
    union { uint32_t u; h2 h; } c;
    c.h = (h2){(_Float16)a, (_Float16)b};
    return c.u;
}

// Workspace layout (bytes): packed weights only.
static constexpr size_t OFF_WT2 = 3072;   // wbits: CO*12 u32 = 3072
static constexpr size_t OFF_A1  = 7168;   // wt2:   16*CO u32 = 4096
static constexpr size_t OFF_CC  = 7424;   // A1/Cc: CO f32 each
static constexpr size_t WS_NEED = 7680;

// Padded s_xb column index: breaks stride-32B bank conflicts, keeps even-col
// 8B alignment for b64 reads.
__device__ __forceinline__ int XB(int c) { return c + ((c >> 3) << 2); }
static constexpr int XBW = 132 + ((132 / 8) << 2) + 4;   // 200 u32 per row

__global__ __launch_bounds__(256) void prep_kernel(
    const float* __restrict__ wbody,
    const float* __restrict__ g1, const float* __restrict__ b1,
    const float* __restrict__ m1, const float* __restrict__ v1,
    const float* __restrict__ wds,
    const float* __restrict__ g2, const float* __restrict__ b2,
    const float* __restrict__ m2, const float* __restrict__ v2,
    uint32_t* __restrict__ wbits, uint32_t* __restrict__ wt2,
    float* __restrict__ A1, float* __restrict__ Cc)
{
    int i = blockIdx.x * 256 + threadIdx.x;
    if (i < 16 * CO) {
        int ci2 = i >> 6, co = i & 63;
        float inv2 = g2[co] * rsqrtf(v2[co] + EPS);
        float w0 = wds[co * CI + 2 * ci2]     * inv2;
        float w1 = wds[co * CI + 2 * ci2 + 1] * inv2;
        wt2[i] = pack_h2(w0, w1);
    } else if (i < 16 * CO + CO * 9) {
        int j = i - 16 * CO;
        int co = j / 9, k = j % 9;
        uint32_t bits = 0u;
#pragma unroll
        for (int ci = 0; ci < CI; ++ci) {
            float wv = wbody[(co * CI + ci) * 9 + k];
            bits |= (uint32_t)(wv >= 0.0f) << ci;
        }
        wbits[co * 12 + k] = bits;
    } else if (i < 16 * CO + CO * 9 + CO) {
        int co = i - 16 * CO - CO * 9;
        float inv1 = g1[co] * rsqrtf(v1[co] + EPS);
        float inv2 = g2[co] * rsqrtf(v2[co] + EPS);
        A1[co] = -2.0f * inv1;
        Cc[co] = b1[co] - m1[co] * inv1 + b2[co] - m2[co] * inv2 + 288.0f * inv1;
    }
}

// Fused kernel: R4 derive structure (2 output rows / block, 1792 blocks,
// single-burst loads) + MFMA downsample + D-layout-matched popc body.
//   Downsample: D[co][pix] = W[co][ci] * avg[ci][pix] via one
//   v_mfma_f32_16x16x32_f16 per 16x16 tile (K=32 complete).
//   Lane l of wave w: A col co=16w+(l&15); D rows co=16w+4*(l>>4)+j, col pix=l&15.
__global__ __launch_bounds__(256) void fused_kernel(
    const float* __restrict__ x,
    const uint32_t* __restrict__ wbits, const uint32_t* __restrict__ wt2,
    const float* __restrict__ A1p, const float* __restrict__ Ccp,
    float* __restrict__ out)
{
    // XCD-chunked bijective swizzle: 1792 = 8 * 224.
    const int bid  = (blockIdx.x & 7) * 224 + (blockIdx.x >> 3);
    const int tile = bid & 1;
    const int gb   = bid >> 1;
    const int g    = gb % 56;          // row-pair group: output rows 2g, 2g+1
    const int b    = gb / 56;
    const int oh0  = 2 * g;
    const int ow0  = tile * 64;
    const int t    = threadIdx.x;

    // LDS: 4000 + 8704 + 4096 + 3072 + 512 = 20,384 B -> 8 blocks/CU LDS-limit
    __shared__ __align__(16) uint32_t s_xb[5][XBW];     // rows rel -1..3, padded cols
    __shared__ __align__(16) uint32_t s_avg[2][16][68]; // [out-row r][ci2][local ow]
    __shared__ __align__(16) uint32_t s_wt2[16][64];
    __shared__ __align__(16) uint32_t s_wb[CO * 12];
    __shared__ float s_A1[CO], s_C[CO];

    // ---- Burst 0: weight loads (oldest in vmcnt FIFO, complete first) ----
    uint32_t wtv[4], wbv[3];
    float a1v = 0.f, ccv = 0.f;
#pragma unroll
    for (int i = 0; i < 4; ++i) wtv[i] = wt2[t + 256 * i];
#pragma unroll
    for (int i = 0; i < 3; ++i) wbv[i] = wbits[t + 256 * i];
    if (t < CO) { a1v = A1p[t]; ccv = Ccp[t]; }

    // per-thread derive indexing
    const int pair = t >> 7;        // 0..1 -> input rows 2oh0+2pair, +1
    const int q    = t & 3;         // ci quarter (ci = 8q..8q+7)
    const int f    = (t >> 2) & 31; // float4 col group: in-cols 2ow0+4f..+3
    const int jcol = 2 * ow0 + 4 * f;
    const bool colok = (jcol + 3 < WI);

    // ---- Burst 1: 16 main-row float4 loads ----
    const float* xp = x + ((size_t)(b * CI + 8 * q) * HI + (oh0 * 2 + 2 * pair)) * WI + jcol;
    float4 L[16];
#pragma unroll
    for (int i = 0; i < 16; ++i) L[i] = make_float4(0.f, 0.f, 0.f, 0.f);
    if (colok) {
#pragma unroll
        for (int k = 0; k < 4; ++k) {
            L[4 * k + 0] = *(const float4*)(xp + (size_t)(2 * k) * HW);
            L[4 * k + 1] = *(const float4*)(xp + (size_t)(2 * k) * HW + WI);
            L[4 * k + 2] = *(const float4*)(xp + (size_t)(2 * k + 1) * HW);
            L[4 * k + 3] = *(const float4*)(xp + (size_t)(2 * k + 1) * HW + WI);
        }
    }

    // ---- Burst 2: 8 halo-row float4 loads (threads 0..127) ----
    float4 H[8];
#pragma unroll
    for (int i = 0; i < 8; ++i) H[i] = make_float4(0.f, 0.f, 0.f, 0.f);
    if (t < 128 && g > 0 && colok) {
        const float* xh = x + ((size_t)(b * CI + 8 * q) * HI + (oh0 * 2 - 1)) * WI + jcol;
#pragma unroll
        for (int k = 0; k < 8; ++k)
            H[k] = *(const float4*)(xh + (size_t)k * HW);
    }

    // ---- Burst 3: 4 halo-col scalar loads (threads 0..39) ----
    const int wc = 2 * ow0 - 1;
    float hv[4] = {-1.f, -1.f, -1.f, -1.f};
    const int lr = t >> 3, lch = t & 7;          // only meaningful for t<40
    const int hr = oh0 * 2 - 1 + lr;
    if (t < 40 && hr >= 0 && wc >= 0) {
        const float* xc = x + ((size_t)(b * CI + 4 * lch) * HI + hr) * WI + wc;
#pragma unroll
        for (int ci = 0; ci < 4; ++ci) hv[ci] = xc[(size_t)ci * HW];
    }

    // ---- Store weights to LDS (waits only on burst-0 FIFO entries) ----
    {
        uint32_t* wt2s = (uint32_t*)s_wt2;
#pragma unroll
        for (int i = 0; i < 4; ++i) wt2s[t + 256 * i] = wtv[i];
#pragma unroll
        for (int i = 0; i < 3; ++i) s_wb[t + 256 * i] = wbv[i];
        if (t < CO) { s_A1[t] = a1v; s_C[t] = ccv; }
    }

    // ---- Process main rows (bits + avgpool) ----
    {
        uint32_t m0[4] = {0, 0, 0, 0}, m1r[4] = {0, 0, 0, 0};
#pragma unroll
        for (int k = 0; k < 4; ++k) {
            const float4 t0 = L[4 * k + 0], u0 = L[4 * k + 1];
            const float4 t1 = L[4 * k + 2], u1 = L[4 * k + 3];
            const int s0 = 8 * q + 2 * k, s1 = s0 + 1;
            m0[0]  |= ((uint32_t)(t0.x >= 0.f) << s0) | ((uint32_t)(t1.x >= 0.f) << s1);
            m0[1]  |= ((uint32_t)(t0.y >= 0.f) << s0) | ((uint32_t)(t1.y >= 0.f) << s1);
            m0[2]  |= ((uint32_t)(t0.z >= 0.f) << s0) | ((uint32_t)(t1.z >= 0.f) << s1);
            m0[3]  |= ((uint32_t)(t0.w >= 0.f) << s0) | ((uint32_t)(t1.w >= 0.f) << s1);
            m1r[0] |= ((uint32_t)(u0.x >= 0.f) << s0) | ((uint32_t)(u1.x >= 0.f) << s1);
            m1r[1] |= ((uint32_t)(u0.y >= 0.f) << s0) | ((uint32_t)(u1.y >= 0.f) << s1);
            m1r[2] |= ((uint32_t)(u0.z >= 0.f) << s0) | ((uint32_t)(u1.z >= 0.f) << s1);
            m1r[3] |= ((uint32_t)(u0.w >= 0.f) << s0) | ((uint32_t)(u1.w >= 0.f) << s1);
            float a0p0 = 0.25f * ((t0.x + t0.y) + (u0.x + u0.y));
            float a0p1 = 0.25f * ((t0.z + t0.w) + (u0.z + u0.w));
            float a1p0 = 0.25f * ((t1.x + t1.y) + (u1.x + u1.y));
            float a1p1 = 0.25f * ((t1.z + t1.w) + (u1.z + u1.w));
            *(uint2*)&s_avg[pair][4 * q + k][2 * f] =
                make_uint2(pack_h2(a0p0, a1p0), pack_h2(a0p1, a1p1));
        }
#pragma unroll
        for (int j = 0; j < 4; ++j) {
            m0[j]  |= __shfl_xor(m0[j], 1);  m0[j]  |= __shfl_xor(m0[j], 2);
            m1r[j] |= __shfl_xor(m1r[j], 1); m1r[j] |= __shfl_xor(m1r[j], 2);
        }
        uint32_t v0  = (q == 0) ? m0[0]  : (q == 1) ? m0[1]  : (q == 2) ? m0[2]  : m0[3];
        uint32_t v1v = (q == 0) ? m1r[0] : (q == 1) ? m1r[1] : (q == 2) ? m1r[2] : m1r[3];
        s_xb[1 + 2 * pair][XB(1 + 4 * f + q)] = v0;
        s_xb[2 + 2 * pair][XB(1 + 4 * f + q)] = v1v;
    }

    // ---- Process halo row (threads 0..127) ----
    if (t < 128) {
        uint32_t mm[4] = {0, 0, 0, 0};
#pragma unroll
        for (int k = 0; k < 4; ++k) {
            const float4 t0 = H[2 * k], t1 = H[2 * k + 1];
            const int s0 = 8 * q + 2 * k, s1 = s0 + 1;
            mm[0] |= ((uint32_t)(t0.x >= 0.f) << s0) | ((uint32_t)(t1.x >= 0.f) << s1);
            mm[1] |= ((uint32_t)(t0.y >= 0.f) << s0) | ((uint32_t)(t1.y >= 0.f) << s1);
            mm[2] |= ((uint32_t)(t0.z >= 0.f) << s0) | ((uint32_t)(t1.z >= 0.f) << s1);
            mm[3] |= ((uint32_t)(t0.w >= 0.f) << s0) | ((uint32_t)(t1.w >= 0.f) << s1);
        }
        if (!(g > 0 && colok)) { mm[0] = mm[1] = mm[2] = mm[3] = 0u; }
#pragma unroll
        for (int j = 0; j < 4; ++j) { mm[j] |= __shfl_xor(mm[j], 1); mm[j] |= __shfl_xor(mm[j], 2); }
        s_xb[0][XB(1 + 4 * f + q)] = (q == 0) ? mm[0] : (q == 1) ? mm[1] : (q == 2) ? mm[2] : mm[3];
    }
    // ---- Process halo column (threads 0..39) ----
    if (t < 40) {
        uint32_t bits = 0u;
        if (hr >= 0 && wc >= 0) {
#pragma unroll
            for (int ci = 0; ci < 4; ++ci)
                bits |= (uint32_t)(hv[ci] >= 0.0f) << (4 * lch + ci);
        }
        bits |= __shfl_xor(bits, 1);
        bits |= __shfl_xor(bits, 2);
        bits |= __shfl_xor(bits, 4);
        if (lch == 0) s_xb[lr][XB(0)] = bits;
    }
    __syncthreads();

    // ---------------- Phase 2: MFMA downsample + D-layout popc body ----------
    const int w   = t >> 6;          // wave id = co tile (co base 16w)
    const int l15 = t & 15;          // D col = pixel within tile; A col = co
    const int lk  = (t >> 4) & 3;    // k-slice group; D row group

    // A fragment (weights): A[m=co=16w+l15][k=8lk+2i..+1] = s_wt2[4lk+i][16w+l15]
    union U8 { uint32_t u[4]; h8 h; };
    U8 af;
#pragma unroll
    for (int i = 0; i < 4; ++i) af.u[i] = s_wt2[4 * lk + i][16 * w + l15];

    // body weights + BN constants for co_j = 16w + 4lk + j
    uint32_t wv[4][9];
    float n2a[4], ccs[4];
#pragma unroll
    for (int j = 0; j < 4; ++j) {
        const int co = 16 * w + 4 * lk + j;
        uint4 wa  = *(const uint4*)&s_wb[co * 12];
        uint4 wb4 = *(const uint4*)&s_wb[co * 12 + 4];
        wv[j][0] = wa.x;  wv[j][1] = wa.y;  wv[j][2] = wa.z;  wv[j][3] = wa.w;
        wv[j][4] = wb4.x; wv[j][5] = wb4.y; wv[j][6] = wb4.z; wv[j][7] = wb4.w;
        wv[j][8] = s_wb[co * 12 + 8];
        n2a[j] = s_A1[co]; ccs[j] = s_C[co];
    }

    const int npt = (tile == 0) ? 4 : 3;   // tile1 pixel-tile 3 is fully OOB

#pragma unroll 1
    for (int r = 0; r < 2; ++r) {
        const bool ohf = (g == 0 && r == 0);
#pragma unroll 1
        for (int pt = 0; pt < npt; ++pt) {
            // B fragment: B[k=8lk+2i..+1][n=pix=16pt+l15]
            U8 bf;
#pragma unroll
            for (int i = 0; i < 4; ++i) bf.u[i] = s_avg[r][4 * lk + i][16 * pt + l15];
            f32x4 acc = {0.f, 0.f, 0.f, 0.f};
            acc = __builtin_amdgcn_mfma_f32_16x16x32_f16(af.h, bf.h, acc, 0, 0, 0);

            // body taps for pixel p_rel = 16pt + l15: s_xb cols c0, c0+1, c0+2
            const int c0 = 32 * pt + 2 * l15;
            const int i0 = XB(c0);         // even -> 8B aligned; c0,c0+1 same 8-block
            const int i2 = XB(c0 + 2);
            uint32_t xr[3][3];
#pragma unroll
            for (int rI = 0; rI < 3; ++rI) {
                const uint32_t* row = s_xb[2 * r + rI];
                uint2 v = *(const uint2*)&row[i0];
                xr[rI][0] = v.x; xr[rI][1] = v.y; xr[rI][2] = row[i2];
            }

            const bool pleft = (tile == 0 && pt == 0 && l15 == 0);
            float res[4];
#pragma unroll
            for (int j = 0; j < 4; ++j) {
                int c00 = __popc(xr[0][0] ^ wv[j][0]);
                int c01 = __popc(xr[0][1] ^ wv[j][1]);
                int c02 = __popc(xr[0][2] ^ wv[j][2]);
                int c10 = __popc(xr[1][0] ^ wv[j][3]);
                int c11 = __popc(xr[1][1] ^ wv[j][4]);
                int c12 = __popc(xr[1][2] ^ wv[j][5]);
                int c20 = __popc(xr[2][0] ^ wv[j][6]);
                int c21 = __popc(xr[2][1] ^ wv[j][7]);
                int c22 = __popc(xr[2][2] ^ wv[j][8]);
                int r0v  = c00 + c01 + c02;
                int ssum = r0v + c10 + c11 + c12 + c20 + c21 + c22;
                if (ohf) ssum += 48 - r0v;               // top image row
                if (pleft) {                             // left image column
                    ssum += 48 - (c00 + c10 + c20);
                    if (ohf) ssum += c00 - 16;           // corner double-fix
                }
                res[j] = fmaf(n2a[j], (float)ssum, acc[j] + ccs[j]);
            }
            // store: co rows 16w+4lk+j, pixel ow0+16pt+l15 (coalesced per l15 group)
            const size_t pbase = (size_t)ow0 + 16 * pt + l15;
#pragma unroll
            for (int j = 0; j < 4; ++j) {
                const int co = 16 * w + 4 * lk + j;
                out[((size_t)(b * CO + co) * HO + (oh0 + r)) * WO + pbase] = res[j];
            }
        }
    }
}

// Fallback if workspace is too small: direct per-output computation (slow, correct).
__global__ __launch_bounds__(256) void naive_kernel(
    const float* __restrict__ x, const float* __restrict__ wbody,
    const float* __restrict__ g1, const float* __restrict__ b1,
    const float* __restrict__ m1, const float* __restrict__ v1,
    const float* __restrict__ wds,
    const float* __restrict__ g2, const float* __restrict__ b2,
    const float* __restrict__ m2, const float* __restrict__ v2,
    float* __restrict__ out)
{
    int i = blockIdx.x * 256 + threadIdx.x;
    if (i >= NB * CO * HO * WO) return;
    int ow = i % WO;
    int oh = (i / WO) % HO;
    int co = (i / (WO * HO)) % CO;
    int b  = i / (WO * HO * CO);
    float inv1 = g1[co] * rsqrtf(v1[co] + EPS);
    float inv2 = g2[co] * rsqrtf(v2[co] + EPS);
    int body = 0;
    float ds = 0.f;
    for (int ci = 0; ci < CI; ++ci) {
        const float* xp = x + (size_t)(b * CI + ci) * HW;
        for (int kh = 0; kh < 3; ++kh) {
            int hh = 2 * oh - 1 + kh;
            if (hh < 0 || hh >= HI) continue;
            for (int kw = 0; kw < 3; ++kw) {
                int ww = 2 * ow - 1 + kw;
                if (ww < 0 || ww >= WI) continue;
                float xv = xp[(size_t)hh * WI + ww];
                float wv = wbody[((co * CI + ci) * 3 + kh) * 3 + kw];
                int sx = (xv >= 0.f) ? 1 : -1;
                int sw = (wv >= 0.f) ? 1 : -1;
                body += sx * sw;
            }
        }
        float a = 0.25f * (xp[(size_t)(2 * oh) * WI + 2 * ow]
                         + xp[(size_t)(2 * oh) * WI + 2 * ow + 1]
                         + xp[(size_t)(2 * oh + 1) * WI + 2 * ow]
                         + xp[(size_t)(2 * oh + 1) * WI + 2 * ow + 1]);
        ds += a * wds[co * CI + ci];
    }
    out[i] = inv1 * (float)body + (b1[co] - m1[co] * inv1)
           + inv2 * ds + (b2[co] - m2[co] * inv2);
}

extern "C" void kernel_launch(void* const* d_in, const int* in_sizes, int n_in,
                              void* d_out, int out_size, void* d_ws, size_t ws_size,
                              hipStream_t stream)
{
    (void)in_sizes; (void)n_in; (void)out_size;
    const float* x   = (const float*)d_in[0];
    const float* wbd = (const float*)d_in[1];
    const float* g1  = (const float*)d_in[2];
    const float* b1  = (const float*)d_in[3];
    const float* m1  = (const float*)d_in[4];
    const float* v1  = (const float*)d_in[5];
    const float* wds = (const float*)d_in[6];
    const float* g2  = (const float*)d_in[7];
    const float* b2  = (const float*)d_in[8];
    const float* m2  = (const float*)d_in[9];
    const float* v2  = (const float*)d_in[10];
    float* out = (float*)d_out;

    if (ws_size < WS_NEED) {
        int total = NB * CO * HO * WO;
        naive_kernel<<<(total + 255) / 256, 256, 0, stream>>>(
            x, wbd, g1, b1, m1, v1, wds, g2, b2, m2, v2, out);
        return;
    }

    char* wsb = (char*)d_ws;
    uint32_t* wbits = (uint32_t*)wsb;
    uint32_t* wt2   = (uint32_t*)(wsb + OFF_WT2);
    float*    A1    = (float*)(wsb + OFF_A1);
    float*    Cc    = (float*)(wsb + OFF_CC);

    prep_kernel<<<7, 256, 0, stream>>>(wbd, g1, b1, m1, v1, wds, g2, b2, m2, v2,
                                       wbits, wt2, A1, Cc);
    // grid = NB * 56 row-pair groups * 2 ow tiles = 1792 blocks (= 8 * 224)
    fused_kernel<<<dim3(NB * 56 * 2), 256, 0, stream>>>(
        x, wbits, wt2, A1, Cc, out);
}